// Round 14
// baseline (309.076 us; speedup 1.0000x reference)
//
#include <hip/hip_runtime.h>

#define BDIM 2
#define SDIM 2048
#define DDIM 2048
#define HQ 16
#define HKV 4
#define DKH 128
#define NKV 512      // HKV*DKH
#define NQKV 3072    // DDIM + 2*NKV; also qkv buffer pitch
#define MROWS 4096   // B*S

typedef __attribute__((ext_vector_type(8))) short bf16x8;
typedef __attribute__((ext_vector_type(4))) float f32x4;
typedef __attribute__((ext_vector_type(8))) unsigned short u16x8;
typedef __attribute__((ext_vector_type(4))) unsigned short u16x4;

#define AS1 __attribute__((address_space(1)))
#define AS3 __attribute__((address_space(3)))

__device__ __forceinline__ unsigned short f2bf(float f) {
    union { float f; unsigned int u; } v; v.f = f;
    unsigned int r = v.u + 0x7FFFu + ((v.u >> 16) & 1u);
    return (unsigned short)(r >> 16);
}
__device__ __forceinline__ float bf2f(unsigned short u) {
    union { unsigned int u; float f; } v; v.u = ((unsigned int)u) << 16;
    return v.f;
}
__device__ __forceinline__ unsigned int pack2bf(float a, float b) {
    return (unsigned int)f2bf(a) | ((unsigned int)f2bf(b) << 16);
}

// ---------------- fused cast f32->bf16 for x|wq|wk|wv|wo + bias concat ----------------
#define NX   ((size_t)MROWS * DDIM)            // 8388608
#define NWQ  ((size_t)DDIM * DDIM)             // 4194304
#define NWKV ((size_t)NKV * DDIM)              // 1048576
#define CAST_BLOCKS 18432                      // (NX+2*NWQ+2*NWKV)/4/256
__global__ void cast_all(const float* __restrict__ x, const float* __restrict__ wq,
                         const float* __restrict__ wk, const float* __restrict__ wv,
                         const float* __restrict__ wo, unsigned short* __restrict__ dst,
                         const float* __restrict__ qb, const float* __restrict__ kb,
                         const float* __restrict__ vb, float* __restrict__ b3) {
    if (blockIdx.x >= CAST_BLOCKS) {           // bias concat tail
        int i = (blockIdx.x - CAST_BLOCKS) * 256 + threadIdx.x;
        if (i < DDIM) b3[i] = qb[i];
        else if (i < DDIM + NKV) b3[i] = kb[i - DDIM];
        else if (i < NQKV) b3[i] = vb[i - DDIM - NKV];
        return;
    }
    size_t i = ((size_t)blockIdx.x * blockDim.x + threadIdx.x) * 4;
    const size_t N0 = NX, N1 = N0 + NWQ, N2 = N1 + NWKV, N3 = N2 + NWKV;
    const float* src; size_t off;
    if (i < N0)      { src = x;  off = i; }
    else if (i < N1) { src = wq; off = i - N0; }
    else if (i < N2) { src = wk; off = i - N1; }
    else if (i < N3) { src = wv; off = i - N2; }
    else             { src = wo; off = i - N3; }
    float4 v = *(const float4*)(src + off);
    u16x4 o;
    o[0] = f2bf(v.x); o[1] = f2bf(v.y); o[2] = f2bf(v.z); o[3] = f2bf(v.w);
    *(u16x4*)(dst + i) = o;
}

// ---------------- V sigma-transpose only (RoPE now fused into QKV GEMM epilogue) ------
__global__ void v_trans(const unsigned short* __restrict__ buf,
                        unsigned short* __restrict__ Vt) {
    __shared__ unsigned short T[32][33];
    int t = blockIdx.x;
    int s0 = (t & 63) * 32, d0 = ((t >> 6) & 15) * 32, b = t >> 10;
    int c = threadIdx.x & 31, r4 = threadIdx.x >> 5;
    for (int rr = r4; rr < 32; rr += 8)
        T[rr][c] = buf[(size_t)(b * SDIM + s0 + rr) * NQKV + (DDIM + NKV) + d0 + c];
    __syncthreads();
    int cp = ((c & 0x0C) << 1) | ((c & 0x10) >> 2) | (c & 3);
    for (int rr = r4; rr < 32; rr += 8)
        Vt[(size_t)(b * NKV + d0 + rr) * SDIM + s0 + cp] = T[c][rr];
}

// ---------------- GEMM: register-pipelined tiles, BK=32, triple-buffered LDS ----------
// r13-measured best for QKV (62.8 us). r14 adds ROPE template: apply RoPE + q-scale in
// the epilogue (pairs are adjacent columns -> partner via __shfl_xor(v,1); cos/sin from
// L2-resident tables; V columns pass through). Kills the separate 25MB rope pass.
template <int BF16OUT, int BM, int BN, int WM, int WN, int ROPE>
__global__ __launch_bounds__(512, 2) void gemm_rp(
    const unsigned short* __restrict__ A,
    const unsigned short* __restrict__ Bm,
    const float* __restrict__ bias,
    void* __restrict__ Cv,
    int pitch, int Kdim,
    const float* __restrict__ cosT, const float* __restrict__ sinT, float qscale) {
    constexpr int MF = BM / WM / 16;      // m-frags per wave
    constexpr int NF = BN / WN / 16;      // n-frags per wave
    constexpr int AI = BM / 128;          // A load-instrs per tile per thread
    constexpr int BI = BN / 128;          // B load-instrs per tile per thread
    constexpr int L  = AI + BI;           // loads per tile (vmcnt count)
    constexpr int BUFS = (BM + BN) * 32;  // shorts per buffer

    __shared__ unsigned short Ls[3 * BUFS];

    const int tid = threadIdx.x;
    const int lane = tid & 63;
    const int wid = tid >> 6;
    const int ml = lane & 15, quad = lane >> 4;
    const int wm = wid / WN, wn = wid % WN;

    // T1: XCD-chunked bijective block swizzle (nwg == 256 for both launches)
    const int gx = gridDim.x;
    const int nwg = gx * gridDim.y;
    int w0 = blockIdx.y * gx + blockIdx.x;
    int wsw = (nwg & 7) ? w0 : ((w0 & 7) * (nwg >> 3) + (w0 >> 3));
    const int m0 = (wsw / gx) * BM, n0 = (wsw % gx) * BN;

    const int NT = Kdim >> 5;             // K-step = 32

    // staging: thread t -> row t>>2 (+128 per extra instr), slot (t&3)^((t>>3)&3)
    const int sr = tid >> 2;
    const int sk = ((tid & 3) ^ ((tid >> 3) & 3)) * 8;
    const unsigned short* Ag0 = A + (size_t)(m0 + sr) * Kdim + sk;
    const unsigned short* Bg0 = Bm + (size_t)(n0 + sr) * Kdim + sk;

    // read-side: frag rows are base(mult of 16)+ml -> swizzle xor = (ml>>1)&3
    const int xsl = (quad ^ ((ml >> 1) & 3)) * 8;
    const int afr0 = wm * (BM / WM) + ml;            // + mf*16
    const int bfr0 = BM * 32 + (wn * (BN / WN) + ml) * 32;  // shorts base for B rows

    f32x4 acc[MF][NF] = {};
    bf16x8 afA[MF], bfA[NF], afB[MF], bfB[NF];

#define STAGE(ib, kt2)                                                                          \
    do {                                                                                        \
        unsigned short* lb = &Ls[(ib) * BUFS];                                                  \
        _Pragma("unroll")                                                                       \
        for (int ll = 0; ll < AI; ++ll)                                                         \
            __builtin_amdgcn_global_load_lds(                                                   \
                (const AS1 unsigned int*)(Ag0 + (size_t)(ll * 128) * Kdim + (kt2)),             \
                (AS3 unsigned int*)(lb + ll * 4096 + tid * 8), 16, 0, 0);                       \
        _Pragma("unroll")                                                                       \
        for (int ll = 0; ll < BI; ++ll)                                                         \
            __builtin_amdgcn_global_load_lds(                                                   \
                (const AS1 unsigned int*)(Bg0 + (size_t)(ll * 128) * Kdim + (kt2)),             \
                (AS3 unsigned int*)(lb + BM * 32 + ll * 4096 + tid * 8), 16, 0, 0);             \
    } while (0)
#define READF(afX, bfX, ib)                                                                     \
    do {                                                                                        \
        const unsigned short* lb = &Ls[(ib) * BUFS];                                            \
        _Pragma("unroll")                                                                       \
        for (int mf = 0; mf < MF; ++mf)                                                         \
            afX[mf] = *(const bf16x8*)(lb + (afr0 + mf * 16) * 32 + xsl);                       \
        _Pragma("unroll")                                                                       \
        for (int nf = 0; nf < NF; ++nf)                                                         \
            bfX[nf] = *(const bf16x8*)(lb + bfr0 + nf * 16 * 32 + xsl);                         \
    } while (0)
#define MMALL(afX, bfX)                                                                         \
    do {                                                                                        \
        _Pragma("unroll")                                                                       \
        for (int mf = 0; mf < MF; ++mf)                                                         \
            _Pragma("unroll")                                                                   \
            for (int nf = 0; nf < NF; ++nf)                                                     \
                acc[mf][nf] = __builtin_amdgcn_mfma_f32_16x16x32_bf16(                          \
                    afX[mf], bfX[nf], acc[mf][nf], 0, 0, 0);                                    \
    } while (0)
#define WAIT_VM_L()                                                                             \
    do {                                                                                        \
        if constexpr (L == 3) asm volatile("s_waitcnt vmcnt(3)" ::: "memory");                  \
        else                  asm volatile("s_waitcnt vmcnt(4)" ::: "memory");                  \
    } while (0)
#define BODY(CAF, CBF, NAF, NBF, G)                                                             \
    do {                                                                                        \
        const int Gs = (G) + 2, Gr = (G) + 1;                                                   \
        if (Gs < NT) { STAGE(Gs % 3, Gs * 32); WAIT_VM_L(); }                                   \
        else         { asm volatile("s_waitcnt vmcnt(0)" ::: "memory"); }                       \
        __builtin_amdgcn_sched_barrier(0);                                                      \
        __builtin_amdgcn_s_barrier();                                                           \
        READF(NAF, NBF, Gr % 3);                                                                \
        __builtin_amdgcn_s_setprio(1);                                                          \
        MMALL(CAF, CBF);                                                                        \
        __builtin_amdgcn_s_setprio(0);                                                          \
        asm volatile("s_waitcnt lgkmcnt(0)" ::: "memory");                                      \
        __builtin_amdgcn_sched_barrier(0);                                                      \
    } while (0)

    // prologue: stage tiles 0,1; retire tile 0 (keep tile 1 in flight); read frags(0)
    STAGE(0, 0);
    STAGE(1, 32);
    WAIT_VM_L();
    __builtin_amdgcn_s_barrier();
    READF(afA, bfA, 0);
    asm volatile("s_waitcnt lgkmcnt(0)" ::: "memory");
    __builtin_amdgcn_sched_barrier(0);

    for (int G = 0; G < NT; G += 2) {
        BODY(afA, bfA, afB, bfB, G);        // compute tile G, prefetch G+1 into B-set
        BODY(afB, bfB, afA, bfA, G + 1);    // compute tile G+1, prefetch G+2 into A-set
    }
#undef STAGE
#undef READF
#undef MMALL
#undef WAIT_VM_L
#undef BODY

    // epilogue: bias add (+ fused RoPE/scale when ROPE) + store
#pragma unroll
    for (int nf = 0; nf < NF; ++nf) {
        const int col = n0 + wn * (BN / WN) + nf * 16 + ml;
        const float bj = bias[col];
        const bool doRope = ROPE && (col < DDIM + NKV);     // Q,K yes; V no (16-aligned)
        const float sc = (ROPE && col < DDIM) ? qscale : 1.f;
        const int i0 = (col & 127) >> 1;
#pragma unroll
        for (int mf = 0; mf < MF; ++mf) {
            const int row0 = m0 + wm * (BM / WM) + mf * 16 + quad * 4;
#pragma unroll
            for (int rr = 0; rr < 4; ++rr) {
                float v = acc[mf][nf][rr] + bj;
                if constexpr (ROPE) {
                    float vp = __shfl_xor(v, 1);            // pair = adjacent column
                    if (doRope) {
                        const int pos = (row0 + rr) & (SDIM - 1);
                        const float c = cosT[pos * 64 + i0];
                        const float s = sinT[pos * 64 + i0];
                        v = (col & 1) ? (vp * s + v * c) : (v * c - vp * s);
                    }
                    v *= sc;
                }
                if (BF16OUT)
                    ((unsigned short*)Cv)[(size_t)(row0 + rr) * pitch + col] = f2bf(v);
                else
                    ((float*)Cv)[(size_t)(row0 + rr) * pitch + col] = v;
            }
        }
    }
}

// ---------------- GEMM variant B: 2-barrier register-pipelined tile (r11 out-proj) ----
template <int BF16OUT, int BM, int BN, int WM, int WN>
__global__ __launch_bounds__(512, 2) void gemm2b(
    const unsigned short* __restrict__ A,
    const unsigned short* __restrict__ Bm,
    const float* __restrict__ bias,
    void* __restrict__ Cv,
    int pitch, int Kdim) {
    constexpr int MF = BM / WM / 16;
    constexpr int NFRAG = BN / WN / 16;
    constexpr int AH = BM / 128;
    constexpr int BH = BN / 128;
    constexpr int AHR = BM / 2;
    constexpr int BHR = BN / 2;

    __shared__ unsigned short As[2][2][AHR * 64];
    __shared__ unsigned short Bs[2][2][BHR * 64];

    const int tid = threadIdx.x;
    const int lane = tid & 63;
    const int wid = tid >> 6;
    const int ml = lane & 15, quad = lane >> 4;
    const int wm = wid / WN, wn = wid % WN;
    const int bhf = wn / (WN / 2);
    const int brb = (wn % (WN / 2)) * (BN / WN);

    const int gx = gridDim.x;
    const int nwg = gx * gridDim.y;
    int w0 = blockIdx.y * gx + blockIdx.x;
    int wsw = (nwg & 7) ? w0 : ((w0 & 7) * (nwg >> 3) + (w0 >> 3));
    const int m0 = (wsw / gx) * BM, n0 = (wsw % gx) * BN;

    const int NT = Kdim >> 6;
    const int xr = ml & 7;

    const int sr = tid >> 3;
    const int sk = ((tid & 7) ^ (sr & 7)) * 8;
    const unsigned short* Ag0 = A + (size_t)(m0 + sr) * Kdim + sk;
    const unsigned short* Bg0 = Bm + (size_t)(n0 + sr) * Kdim + sk;

    f32x4 acc[MF][NFRAG] = {};

#define STG_A(bf, hf, kt)                                                                       \
    do {                                                                                        \
        _Pragma("unroll")                                                                       \
        for (int ll = 0; ll < AH; ++ll)                                                         \
            __builtin_amdgcn_global_load_lds(                                                   \
                (const AS1 unsigned int*)(Ag0 + (size_t)((hf) * AHR + ll * 64) * Kdim + (kt)),  \
                (AS3 unsigned int*)(&As[bf][hf][ll * 4096 + tid * 8]), 16, 0, 0);               \
    } while (0)
#define STG_B(bf, hf, kt)                                                                       \
    do {                                                                                        \
        _Pragma("unroll")                                                                       \
        for (int ll = 0; ll < BH; ++ll)                                                         \
            __builtin_amdgcn_global_load_lds(                                                   \
                (const AS1 unsigned int*)(Bg0 + (size_t)((hf) * BHR + ll * 64) * Kdim + (kt)),  \
                (AS3 unsigned int*)(&Bs[bf][hf][ll * 4096 + tid * 8]), 16, 0, 0);               \
    } while (0)
#define WAIT_VM_STEADY()                                                                        \
    do {                                                                                        \
        if constexpr (BH == 1)      asm volatile("s_waitcnt vmcnt(2)" ::: "memory");            \
        else if constexpr (BH == 2) asm volatile("s_waitcnt vmcnt(4)" ::: "memory");            \
        else                        asm volatile("s_waitcnt vmcnt(6)" ::: "memory");            \
    } while (0)

    STG_B(0, 0, 0); STG_B(0, 1, 0);
    STG_A(0, 0, 0); STG_A(0, 1, 0);
    if (NT > 1) {
        STG_B(1, 0, 64); STG_B(1, 1, 64);
        WAIT_VM_STEADY();
    } else {
        asm volatile("s_waitcnt vmcnt(0)" ::: "memory");
    }
    __builtin_amdgcn_s_barrier();
    __builtin_amdgcn_sched_barrier(0);

    for (int G = 0; G < NT; ++G) {
        const int cur = G & 1, nxt = cur ^ 1;
        const int ktA = (G + 1) * 64, ktB = (G + 2) * 64;
        const unsigned short* Bh = Bs[cur][bhf];

        bf16x8 bfr[NFRAG][2];
#pragma unroll
        for (int nj = 0; nj < NFRAG; ++nj)
#pragma unroll
            for (int kk = 0; kk < 2; ++kk)
                bfr[nj][kk] = *(const bf16x8*)&Bh[(brb + nj * 16 + ml) * 64 + ((kk * 4 + quad) ^ xr) * 8];

        bf16x8 af[MF][2];
#pragma unroll
        for (int mf = 0; mf < MF; ++mf) {
            const int arow0 = wm * (BM / WM) + mf * 16;
            const int ahf = arow0 / AHR;
            const int arin = arow0 % AHR + ml;
#pragma unroll
            for (int kk = 0; kk < 2; ++kk)
                af[mf][kk] = *(const bf16x8*)&As[cur][ahf][arin * 64 + ((kk * 4 + quad) ^ xr) * 8];
        }

        if (G + 1 < NT) { STG_A(nxt, 0, ktA); STG_A(nxt, 1, ktA); }

        __builtin_amdgcn_s_setprio(1);
#pragma unroll
        for (int kk = 0; kk < 2; ++kk)
#pragma unroll
            for (int mf = 0; mf < MF; ++mf)
#pragma unroll
                for (int nj = 0; nj < NFRAG; ++nj)
                    acc[mf][nj] = __builtin_amdgcn_mfma_f32_16x16x32_bf16(
                        af[mf][kk], bfr[nj][kk], acc[mf][nj], 0, 0, 0);
        __builtin_amdgcn_s_setprio(0);

        asm volatile("s_waitcnt lgkmcnt(0)" ::: "memory");
        __builtin_amdgcn_sched_barrier(0);
        __builtin_amdgcn_s_barrier();

        if (G + 2 < NT) { STG_B(cur, 0, ktB); STG_B(cur, 1, ktB); }
        if (G < NT - 2)       { WAIT_VM_STEADY(); }
        else if (G == NT - 2) { asm volatile("s_waitcnt vmcnt(0)" ::: "memory"); }
        __builtin_amdgcn_sched_barrier(0);
        __builtin_amdgcn_s_barrier();
        __builtin_amdgcn_sched_barrier(0);
    }
#undef STG_A
#undef STG_B
#undef WAIT_VM_STEADY

#pragma unroll
    for (int nj = 0; nj < NFRAG; ++nj) {
        const int col = n0 + wn * (BN / WN) + nj * 16 + ml;
        const float bj = bias[col];
#pragma unroll
        for (int mf = 0; mf < MF; ++mf) {
            const int row0 = m0 + wm * (BM / WM) + mf * 16 + quad * 4;
#pragma unroll
            for (int rr = 0; rr < 4; ++rr) {
                float v = acc[mf][nj][rr] + bj;
                if (BF16OUT)
                    ((unsigned short*)Cv)[(size_t)(row0 + rr) * pitch + col] = f2bf(v);
                else
                    ((float*)Cv)[(size_t)(row0 + rr) * pitch + col] = v;
            }
        }
    }
}

// ---------------- Flash attention: pair-split-KV + LDS k-slot XOR swizzle (r11) --------
__global__ __launch_bounds__(256, 2) void attn_fwd(
    const unsigned short* __restrict__ Qp,
    const unsigned short* __restrict__ Kp,
    const unsigned short* __restrict__ Vt,
    unsigned short* __restrict__ O) {
    const int l = blockIdx.x;
    const int j = l & 15;                 // low q-tile index (0..15)
    const int h = (l >> 4) & 15;
    const int b = l >> 8;
    const int g = h >> 2;
    const int jh = 31 - j;                // high q-tile index (16..31)
    const int tid = threadIdx.x;
    const int w = tid >> 6, lane = tid & 63;
    const int ml = lane & 15, quad = lane >> 4;
    const int rsub = lane >> 2, seg = lane & 3;
    const int pr = w >> 1;                // pair: 0 = A (high 0..16), 1 = B (low, then high tail)
    const int wsub = w & 1;               // 32-row substrip within the pair's q-tile
    const int ssw = (rsub >> 1) & 3;      // staging-side k-slot swizzle (lane-constant)
    const int xsw = (ml >> 1) & 3;        // read-side k-slot swizzle

    __shared__ unsigned short Ks[2][4 * 64 * 32];   // per-pair K tile [kc][krow][32]
    __shared__ unsigned short Vs[2][2 * 128 * 32];  // per-pair V^T tile (sigma order)

    int myqt = pr ? j : jh;
    int q0 = myqt * 64 + wsub * 32;

    bf16x8 aq[2][4];
    auto load_q = [&](int qt) {
#pragma unroll
        for (int g2 = 0; g2 < 2; ++g2) {
            const size_t qrow = (size_t)(b * SDIM + qt * 64 + wsub * 32 + g2 * 16 + ml);
#pragma unroll
            for (int kc = 0; kc < 4; ++kc)
                aq[g2][kc] = *(const bf16x8*)(Qp + qrow * NQKV + h * DKH + kc * 32 + quad * 8);
        }
    };
    load_q(myqt);

    f32x4 o_acc[2][8] = {};
    float l_acc[2] = {0.f, 0.f};

    auto store_out = [&](int qt) {
#pragma unroll
        for (int g2 = 0; g2 < 2; ++g2) {
            float lt = l_acc[g2];
            lt += __shfl_xor(lt, 16);
            lt += __shfl_xor(lt, 32);
            float inv = 1.f / lt;
            size_t rowbase = (size_t)(b * SDIM + qt * 64 + wsub * 32 + g2 * 16 + ml) * DDIM + h * DKH + quad * 4;
#pragma unroll
            for (int dt = 0; dt < 8; ++dt) {
                u16x4 ov;
#pragma unroll
                for (int r = 0; r < 4; ++r)
                    ov[r] = f2bf(o_acc[g2][dt][r] * inv);
                *(u16x4*)(O + rowbase + dt * 16) = ov;
            }
        }
    };

    for (int it = 0; it < 17; ++it) {
        // pair-specific KV tile; kt < 0 => idle iteration (barriers only)
        int kt;
        if (pr == 0)       kt = it;                 // pair A: high tiles 0..16
        else if (it <= j)  kt = it;                 // pair B: low tiles 0..j
        else if (it <= 15) kt = 16 + it - j;        // pair B: high tiles 17..31-j
        else               kt = -1;                 // pair B: idle pad

        __syncthreads();
        if (kt >= 0) {
            const int kb = kt * 64;
            // stage K tile 64x128 into Ks[pr]: source k-chunk pre-swizzled by ssw
#pragma unroll
            for (int kc = 0; kc < 4; ++kc)
#pragma unroll
                for (int rh = 0; rh < 2; ++rh)
                    __builtin_amdgcn_global_load_lds(
                        (const AS1 unsigned int*)(Kp + (size_t)(b * SDIM + kb + rh * 32 + wsub * 16 + rsub) * NQKV + g * DKH + kc * 32 + (seg ^ ssw) * 8),
                        (AS3 unsigned int*)(&Ks[pr][kc * 2048 + rh * 1024 + wsub * 512 + lane * 8]), 16, 0, 0);
            // stage V^T tile (128 d x 64 kv): source kv-chunk pre-swizzled by ssw
#pragma unroll
            for (int c = 0; c < 8; ++c) {
                int u = wsub * 8 + c, kc2 = u >> 3, rg = u & 7;
                __builtin_amdgcn_global_load_lds(
                    (const AS1 unsigned int*)(Vt + (size_t)(b * NKV + g * DKH + rg * 16 + rsub) * SDIM + kb + kc2 * 32 + (seg ^ ssw) * 8),
                    (AS3 unsigned int*)(&Vs[pr][u * 512 + lane * 8]), 16, 0, 0);
            }
        }
        __syncthreads();

        // pair B phase switch: low strip complete -> store it, re-arm for high tail
        if (pr == 1 && it == j + 1) {
            store_out(j);
            myqt = jh; q0 = myqt * 64 + wsub * 32;
            load_q(jh);
#pragma unroll
            for (int g2 = 0; g2 < 2; ++g2) {
                l_acc[g2] = 0.f;
#pragma unroll
                for (int dt = 0; dt < 8; ++dt) o_acc[g2][dt] = (f32x4){0.f, 0.f, 0.f, 0.f};
            }
        }

        if (kt >= 0) {
            const int kb = kt * 64;
            __builtin_amdgcn_s_setprio(1);
            // S^T: A=K (m=kv), B=Q (n=q). st[g2][t][r]: kv=kb+16t+4*quad+r, q=q0+g2*16+ml
            f32x4 st[2][4];
#pragma unroll
            for (int t = 0; t < 4; ++t) {
                bf16x8 ak[4];
#pragma unroll
                for (int kc = 0; kc < 4; ++kc)
                    ak[kc] = *(const bf16x8*)&Ks[pr][kc * 2048 + (t * 16 + ml) * 32 + (quad ^ xsw) * 8];
#pragma unroll
                for (int g2 = 0; g2 < 2; ++g2) {
                    f32x4 sc = {};
#pragma unroll
                    for (int kc = 0; kc < 4; ++kc)
                        sc = __builtin_amdgcn_mfma_f32_16x16x32_bf16(ak[kc], aq[g2][kc], sc, 0, 0, 0);
                    st[g2][t] = sc;
                }
            }

            if (kb + 63 > q0) {  // diagonal tile: causal mask
#pragma unroll
                for (int g2 = 0; g2 < 2; ++g2) {
                    int qg = q0 + g2 * 16 + ml;
#pragma unroll
                    for (int t = 0; t < 4; ++t) {
                        int kvb = kb + t * 16 + quad * 4;
#pragma unroll
                        for (int r = 0; r < 4; ++r)
                            if (kvb + r > qg) st[g2][t][r] = -INFINITY;
                    }
                }
            }

            // fixed-m softmax: p = exp(s - 20), accumulate l in-lane
            unsigned int pk[2][4][2];
#pragma unroll
            for (int g2 = 0; g2 < 2; ++g2) {
#pragma unroll
                for (int t = 0; t < 4; ++t) {
                    float p0 = __expf(st[g2][t][0] - 20.f);
                    float p1 = __expf(st[g2][t][1] - 20.f);
                    float p2 = __expf(st[g2][t][2] - 20.f);
                    float p3 = __expf(st[g2][t][3] - 20.f);
                    l_acc[g2] += (p0 + p1) + (p2 + p3);
                    pk[g2][t][0] = pack2bf(p0, p1);
                    pk[g2][t][1] = pack2bf(p2, p3);
                }
            }

            // PV: O^T += V^T * P^T ; each av read feeds both g2 groups
#pragma unroll
            for (int c = 0; c < 2; ++c) {
                union { unsigned int u[4]; bf16x8 v; } pb[2];
#pragma unroll
                for (int g2 = 0; g2 < 2; ++g2) {
                    pb[g2].u[0] = pk[g2][2 * c][0];     pb[g2].u[1] = pk[g2][2 * c][1];
                    pb[g2].u[2] = pk[g2][2 * c + 1][0]; pb[g2].u[3] = pk[g2][2 * c + 1][1];
                }
#pragma unroll
                for (int dt = 0; dt < 8; ++dt) {
                    bf16x8 av = *(const bf16x8*)&Vs[pr][c * 4096 + (dt * 16 + ml) * 32 + (quad ^ xsw) * 8];
                    o_acc[0][dt] = __builtin_amdgcn_mfma_f32_16x16x32_bf16(av, pb[0].v, o_acc[0][dt], 0, 0, 0);
                    o_acc[1][dt] = __builtin_amdgcn_mfma_f32_16x16x32_bf16(av, pb[1].v, o_acc[1][dt], 0, 0, 0);
                }
            }
            __builtin_amdgcn_s_setprio(0);
        }
    }

    // combine: pair A's q_high partial -> pair B (LDS reuse; conflict-balanced f32x4 layout)
    __syncthreads();
    float* Fo = (float*)&Ks[0][0];   // 8192 floats (32 KB) == 2 waves x 64 lanes x 64 f32
    float* Fl = (float*)&Vs[0][0];   // 256 floats
    if (pr == 0) {
#pragma unroll
        for (int g2 = 0; g2 < 2; ++g2) {
            Fl[(g2 * 2 + wsub) * 64 + lane] = l_acc[g2];
#pragma unroll
            for (int dt = 0; dt < 8; ++dt)
                *(f32x4*)&Fo[(g2 * 8 + dt) * 512 + wsub * 256 + lane * 4] = o_acc[g2][dt];
        }
    }
    __syncthreads();
    if (pr == 1) {
#pragma unroll
        for (int g2 = 0; g2 < 2; ++g2) {
            l_acc[g2] += Fl[(g2 * 2 + wsub) * 64 + lane];
#pragma unroll
            for (int dt = 0; dt < 8; ++dt) {
                f32x4 pa = *(const f32x4*)&Fo[(g2 * 8 + dt) * 512 + wsub * 256 + lane * 4];
#pragma unroll
                for (int r = 0; r < 4; ++r) o_acc[g2][dt][r] += pa[r];
            }
        }
        store_out(jh);
    }
}

// ---------------- host launch ----------------
extern "C" void kernel_launch(void* const* d_in, const int* in_sizes, int n_in,
                              void* d_out, int out_size, void* d_ws, size_t ws_size,
                              hipStream_t stream) {
    const float* x    = (const float*)d_in[0];
    const float* fcos = (const float*)d_in[1];
    const float* fsin = (const float*)d_in[2];
    const float* wq_w = (const float*)d_in[3];
    const float* wq_b = (const float*)d_in[4];
    const float* wk_w = (const float*)d_in[5];
    const float* wk_b = (const float*)d_in[6];
    const float* wv_w = (const float*)d_in[7];
    const float* wv_b = (const float*)d_in[8];
    const float* wo_w = (const float*)d_in[9];
    const float* wo_b = (const float*)d_in[10];
    float* out = (float*)d_out;

    char* ws = (char*)d_ws;
    size_t off = 0;
    auto alloc = [&](size_t bytes) {
        char* p = ws + off;
        off += (bytes + 255) & ~(size_t)255;
        return p;
    };
    // NOTE: xb|W3|wob must be contiguous (cast_all writes them as one range)
    unsigned short* xb  = (unsigned short*)alloc(NX * 2);
    unsigned short* W3  = (unsigned short*)alloc((size_t)NQKV * DDIM * 2);
    unsigned short* wob = (unsigned short*)alloc(NWQ * 2);
    float* b3           = (float*)alloc((size_t)NQKV * 4);
    unsigned short* qkv = (unsigned short*)alloc((size_t)MROWS * NQKV * 2);
    unsigned short* Vt  = (unsigned short*)alloc((size_t)BDIM * NKV * SDIM * 2);
    unsigned short* att = (unsigned short*)alloc((size_t)MROWS * DDIM * 2);

    cast_all<<<dim3(CAST_BLOCKS + 12), dim3(256), 0, stream>>>(
        x, wq_w, wk_w, wv_w, wo_w, xb, wq_b, wk_b, wv_b, b3);

    const float scale = 0.08838834764831845f;  // 1/sqrt(128), folded into Q in epilogue

    // fused QKV projection + RoPE + q-scale: 128x384 tile -> 8x32 = 256 blocks
    gemm_rp<1, 128, 384, 1, 8, 1><<<dim3(NQKV / 384, MROWS / 128), 512, 0, stream>>>(
        xb, W3, b3, qkv, NQKV, DDIM, fcos, fsin, scale);

    // V sigma-transpose only (RoPE done in GEMM epilogue)
    v_trans<<<dim3(2048), dim3(256), 0, stream>>>(qkv, Vt);

    attn_fwd<<<dim3(512), dim3(256), 0, stream>>>(qkv, qkv + DDIM, Vt, att);

    // output projection (f32 out): 256x128 tile, 2-barrier (r11 best) -> 256 blocks
    gemm2b<0, 256, 128, 2, 4><<<dim3(DDIM / 128, MROWS / 256), 512, 0, stream>>>(
        att, wob, wo_b, out, DDIM, DDIM);
}

// Round 15
// 288.326 us; speedup vs baseline: 1.0720x; 1.0720x over previous
//
#include <hip/hip_runtime.h>

#define BDIM 2
#define SDIM 2048
#define DDIM 2048
#define HQ 16
#define HKV 4
#define DKH 128
#define NKV 512      // HKV*DKH
#define NQKV 3072    // DDIM + 2*NKV; also qkv buffer pitch
#define MROWS 4096   // B*S

typedef __attribute__((ext_vector_type(8))) short bf16x8;
typedef __attribute__((ext_vector_type(4))) float f32x4;
typedef __attribute__((ext_vector_type(8))) unsigned short u16x8;
typedef __attribute__((ext_vector_type(4))) unsigned short u16x4;

#define AS1 __attribute__((address_space(1)))
#define AS3 __attribute__((address_space(3)))

__device__ __forceinline__ unsigned short f2bf(float f) {
    union { float f; unsigned int u; } v; v.f = f;
    unsigned int r = v.u + 0x7FFFu + ((v.u >> 16) & 1u);
    return (unsigned short)(r >> 16);
}
__device__ __forceinline__ float bf2f(unsigned short u) {
    union { unsigned int u; float f; } v; v.u = ((unsigned int)u) << 16;
    return v.f;
}
__device__ __forceinline__ unsigned int pack2bf(float a, float b) {
    return (unsigned int)f2bf(a) | ((unsigned int)f2bf(b) << 16);
}

// ---------------- fused cast f32->bf16 for x|wq|wk|wv|wo + bias concat ----------------
#define NX   ((size_t)MROWS * DDIM)            // 8388608
#define NWQ  ((size_t)DDIM * DDIM)             // 4194304
#define NWKV ((size_t)NKV * DDIM)              // 1048576
#define CAST_BLOCKS 18432                      // (NX+2*NWQ+2*NWKV)/4/256
__global__ void cast_all(const float* __restrict__ x, const float* __restrict__ wq,
                         const float* __restrict__ wk, const float* __restrict__ wv,
                         const float* __restrict__ wo, unsigned short* __restrict__ dst,
                         const float* __restrict__ qb, const float* __restrict__ kb,
                         const float* __restrict__ vb, float* __restrict__ b3) {
    if (blockIdx.x >= CAST_BLOCKS) {           // bias concat tail
        int i = (blockIdx.x - CAST_BLOCKS) * 256 + threadIdx.x;
        if (i < DDIM) b3[i] = qb[i];
        else if (i < DDIM + NKV) b3[i] = kb[i - DDIM];
        else if (i < NQKV) b3[i] = vb[i - DDIM - NKV];
        return;
    }
    size_t i = ((size_t)blockIdx.x * blockDim.x + threadIdx.x) * 4;
    const size_t N0 = NX, N1 = N0 + NWQ, N2 = N1 + NWKV, N3 = N2 + NWKV;
    const float* src; size_t off;
    if (i < N0)      { src = x;  off = i; }
    else if (i < N1) { src = wq; off = i - N0; }
    else if (i < N2) { src = wk; off = i - N1; }
    else if (i < N3) { src = wv; off = i - N2; }
    else             { src = wo; off = i - N3; }
    float4 v = *(const float4*)(src + off);
    u16x4 o;
    o[0] = f2bf(v.x); o[1] = f2bf(v.y); o[2] = f2bf(v.z); o[3] = f2bf(v.w);
    *(u16x4*)(dst + i) = o;
}

// ---------------- fused RoPE (blocks 0..4095) + sigma V transpose (blocks 4096..6143) ----
__global__ void rope_trans(unsigned short* __restrict__ buf,
                           const float* __restrict__ cosT, const float* __restrict__ sinT,
                           unsigned short* __restrict__ Vt, float qscale) {
    if (blockIdx.x < MROWS) {
        int r = blockIdx.x, pos = r & (SDIM - 1);
        int col0 = threadIdx.x * 8;                 // 320 threads -> cols [0,2560)
        unsigned short* p = buf + (size_t)r * NQKV + col0;
        int i0 = (col0 & 127) >> 1;
        float4 c4 = *(const float4*)(cosT + pos * 64 + i0);
        float4 s4 = *(const float4*)(sinT + pos * 64 + i0);
        float sc = (col0 < DDIM) ? qscale : 1.f;
        u16x8 v = *(const u16x8*)p;
        u16x8 o;
        float cc[4] = {c4.x, c4.y, c4.z, c4.w}, ss[4] = {s4.x, s4.y, s4.z, s4.w};
#pragma unroll
        for (int k = 0; k < 4; ++k) {
            float xr = bf2f(v[2 * k]), xi = bf2f(v[2 * k + 1]);
            o[2 * k]     = f2bf((xr * cc[k] - xi * ss[k]) * sc);
            o[2 * k + 1] = f2bf((xr * ss[k] + xi * cc[k]) * sc);
        }
        *(u16x8*)p = o;
    } else {
        __shared__ unsigned short T[32][33];
        if (threadIdx.x >= 256) return;
        int t = blockIdx.x - MROWS;
        int s0 = (t & 63) * 32, d0 = ((t >> 6) & 15) * 32, b = t >> 10;
        int c = threadIdx.x & 31, r4 = threadIdx.x >> 5;
        for (int rr = r4; rr < 32; rr += 8)
            T[rr][c] = buf[(size_t)(b * SDIM + s0 + rr) * NQKV + (DDIM + NKV) + d0 + c];
        __syncthreads();
        int cp = ((c & 0x0C) << 1) | ((c & 0x10) >> 2) | (c & 3);
        for (int rr = r4; rr < 32; rr += 8)
            Vt[(size_t)(b * NKV + d0 + rr) * SDIM + s0 + cp] = T[c][rr];
    }
}

// ---------------- GEMM (QKV): register-pipelined tiles, BK=32, triple-buffered LDS ----
// r13-measured best for QKV: 62.8 us. Plain epilogue (r14's fused-RoPE variant measured
// +20 us from uncoalesced per-lane cos/sin loads - reverted).
template <int BF16OUT, int BM, int BN, int WM, int WN>
__global__ __launch_bounds__(512, 2) void gemm_rp(
    const unsigned short* __restrict__ A,
    const unsigned short* __restrict__ Bm,
    const float* __restrict__ bias,
    void* __restrict__ Cv,
    int pitch, int Kdim) {
    constexpr int MF = BM / WM / 16;      // m-frags per wave
    constexpr int NF = BN / WN / 16;      // n-frags per wave
    constexpr int AI = BM / 128;          // A load-instrs per tile per thread
    constexpr int BI = BN / 128;          // B load-instrs per tile per thread
    constexpr int L  = AI + BI;           // loads per tile (vmcnt count)
    constexpr int BUFS = (BM + BN) * 32;  // shorts per buffer

    __shared__ unsigned short Ls[3 * BUFS];

    const int tid = threadIdx.x;
    const int lane = tid & 63;
    const int wid = tid >> 6;
    const int ml = lane & 15, quad = lane >> 4;
    const int wm = wid / WN, wn = wid % WN;

    // T1: XCD-chunked bijective block swizzle (nwg == 256)
    const int gx = gridDim.x;
    const int nwg = gx * gridDim.y;
    int w0 = blockIdx.y * gx + blockIdx.x;
    int wsw = (nwg & 7) ? w0 : ((w0 & 7) * (nwg >> 3) + (w0 >> 3));
    const int m0 = (wsw / gx) * BM, n0 = (wsw % gx) * BN;

    const int NT = Kdim >> 5;             // K-step = 32

    // staging: thread t -> row t>>2 (+128 per extra instr), slot (t&3)^((t>>3)&3)
    const int sr = tid >> 2;
    const int sk = ((tid & 3) ^ ((tid >> 3) & 3)) * 8;
    const unsigned short* Ag0 = A + (size_t)(m0 + sr) * Kdim + sk;
    const unsigned short* Bg0 = Bm + (size_t)(n0 + sr) * Kdim + sk;

    // read-side: frag rows are base(mult of 16)+ml -> swizzle xor = (ml>>1)&3
    const int xsl = (quad ^ ((ml >> 1) & 3)) * 8;
    const int afr0 = wm * (BM / WM) + ml;            // + mf*16
    const int bfr0 = BM * 32 + (wn * (BN / WN) + ml) * 32;  // shorts base for B rows

    f32x4 acc[MF][NF] = {};
    bf16x8 afA[MF], bfA[NF], afB[MF], bfB[NF];

#define STAGE(ib, kt2)                                                                          \
    do {                                                                                        \
        unsigned short* lb = &Ls[(ib) * BUFS];                                                  \
        _Pragma("unroll")                                                                       \
        for (int ll = 0; ll < AI; ++ll)                                                         \
            __builtin_amdgcn_global_load_lds(                                                   \
                (const AS1 unsigned int*)(Ag0 + (size_t)(ll * 128) * Kdim + (kt2)),             \
                (AS3 unsigned int*)(lb + ll * 4096 + tid * 8), 16, 0, 0);                       \
        _Pragma("unroll")                                                                       \
        for (int ll = 0; ll < BI; ++ll)                                                         \
            __builtin_amdgcn_global_load_lds(                                                   \
                (const AS1 unsigned int*)(Bg0 + (size_t)(ll * 128) * Kdim + (kt2)),             \
                (AS3 unsigned int*)(lb + BM * 32 + ll * 4096 + tid * 8), 16, 0, 0);             \
    } while (0)
#define READF(afX, bfX, ib)                                                                     \
    do {                                                                                        \
        const unsigned short* lb = &Ls[(ib) * BUFS];                                            \
        _Pragma("unroll")                                                                       \
        for (int mf = 0; mf < MF; ++mf)                                                         \
            afX[mf] = *(const bf16x8*)(lb + (afr0 + mf * 16) * 32 + xsl);                       \
        _Pragma("unroll")                                                                       \
        for (int nf = 0; nf < NF; ++nf)                                                         \
            bfX[nf] = *(const bf16x8*)(lb + bfr0 + nf * 16 * 32 + xsl);                         \
    } while (0)
#define MMALL(afX, bfX)                                                                         \
    do {                                                                                        \
        _Pragma("unroll")                                                                       \
        for (int mf = 0; mf < MF; ++mf)                                                         \
            _Pragma("unroll")                                                                   \
            for (int nf = 0; nf < NF; ++nf)                                                     \
                acc[mf][nf] = __builtin_amdgcn_mfma_f32_16x16x32_bf16(                          \
                    afX[mf], bfX[nf], acc[mf][nf], 0, 0, 0);                                    \
    } while (0)
#define WAIT_VM_L()                                                                             \
    do {                                                                                        \
        if constexpr (L == 3) asm volatile("s_waitcnt vmcnt(3)" ::: "memory");                  \
        else                  asm volatile("s_waitcnt vmcnt(4)" ::: "memory");                  \
    } while (0)
#define BODY(CAF, CBF, NAF, NBF, G)                                                             \
    do {                                                                                        \
        const int Gs = (G) + 2, Gr = (G) + 1;                                                   \
        if (Gs < NT) { STAGE(Gs % 3, Gs * 32); WAIT_VM_L(); }                                   \
        else         { asm volatile("s_waitcnt vmcnt(0)" ::: "memory"); }                       \
        __builtin_amdgcn_sched_barrier(0);                                                      \
        __builtin_amdgcn_s_barrier();                                                           \
        READF(NAF, NBF, Gr % 3);                                                                \
        __builtin_amdgcn_s_setprio(1);                                                          \
        MMALL(CAF, CBF);                                                                        \
        __builtin_amdgcn_s_setprio(0);                                                          \
        asm volatile("s_waitcnt lgkmcnt(0)" ::: "memory");                                      \
        __builtin_amdgcn_sched_barrier(0);                                                      \
    } while (0)

    // prologue: stage tiles 0,1; retire tile 0 (keep tile 1 in flight); read frags(0)
    STAGE(0, 0);
    STAGE(1, 32);
    WAIT_VM_L();
    __builtin_amdgcn_s_barrier();
    READF(afA, bfA, 0);
    asm volatile("s_waitcnt lgkmcnt(0)" ::: "memory");
    __builtin_amdgcn_sched_barrier(0);

    for (int G = 0; G < NT; G += 2) {
        BODY(afA, bfA, afB, bfB, G);        // compute tile G, prefetch G+1 into B-set
        BODY(afB, bfB, afA, bfA, G + 1);    // compute tile G+1, prefetch G+2 into A-set
    }
#undef STAGE
#undef READF
#undef MMALL
#undef WAIT_VM_L
#undef BODY

    // epilogue: bias add + store (C frag layout: row = quad*4+rr, col = ml)
#pragma unroll
    for (int nf = 0; nf < NF; ++nf) {
        const int col = n0 + wn * (BN / WN) + nf * 16 + ml;
        const float bj = bias[col];
#pragma unroll
        for (int mf = 0; mf < MF; ++mf) {
            const int row0 = m0 + wm * (BM / WM) + mf * 16 + quad * 4;
#pragma unroll
            for (int rr = 0; rr < 4; ++rr) {
                float v = acc[mf][nf][rr] + bj;
                if (BF16OUT)
                    ((unsigned short*)Cv)[(size_t)(row0 + rr) * pitch + col] = f2bf(v);
                else
                    ((float*)Cv)[(size_t)(row0 + rr) * pitch + col] = v;
            }
        }
    }
}

// ---------------- GEMM variant B: 2-barrier register-pipelined tile (r11 out-proj) ----
template <int BF16OUT, int BM, int BN, int WM, int WN>
__global__ __launch_bounds__(512, 2) void gemm2b(
    const unsigned short* __restrict__ A,
    const unsigned short* __restrict__ Bm,
    const float* __restrict__ bias,
    void* __restrict__ Cv,
    int pitch, int Kdim) {
    constexpr int MF = BM / WM / 16;
    constexpr int NFRAG = BN / WN / 16;
    constexpr int AH = BM / 128;
    constexpr int BH = BN / 128;
    constexpr int AHR = BM / 2;
    constexpr int BHR = BN / 2;

    __shared__ unsigned short As[2][2][AHR * 64];
    __shared__ unsigned short Bs[2][2][BHR * 64];

    const int tid = threadIdx.x;
    const int lane = tid & 63;
    const int wid = tid >> 6;
    const int ml = lane & 15, quad = lane >> 4;
    const int wm = wid / WN, wn = wid % WN;
    const int bhf = wn / (WN / 2);
    const int brb = (wn % (WN / 2)) * (BN / WN);

    const int gx = gridDim.x;
    const int nwg = gx * gridDim.y;
    int w0 = blockIdx.y * gx + blockIdx.x;
    int wsw = (nwg & 7) ? w0 : ((w0 & 7) * (nwg >> 3) + (w0 >> 3));
    const int m0 = (wsw / gx) * BM, n0 = (wsw % gx) * BN;

    const int NT = Kdim >> 6;
    const int xr = ml & 7;

    const int sr = tid >> 3;
    const int sk = ((tid & 7) ^ (sr & 7)) * 8;
    const unsigned short* Ag0 = A + (size_t)(m0 + sr) * Kdim + sk;
    const unsigned short* Bg0 = Bm + (size_t)(n0 + sr) * Kdim + sk;

    f32x4 acc[MF][NFRAG] = {};

#define STG_A(bf, hf, kt)                                                                       \
    do {                                                                                        \
        _Pragma("unroll")                                                                       \
        for (int ll = 0; ll < AH; ++ll)                                                         \
            __builtin_amdgcn_global_load_lds(                                                   \
                (const AS1 unsigned int*)(Ag0 + (size_t)((hf) * AHR + ll * 64) * Kdim + (kt)),  \
                (AS3 unsigned int*)(&As[bf][hf][ll * 4096 + tid * 8]), 16, 0, 0);               \
    } while (0)
#define STG_B(bf, hf, kt)                                                                       \
    do {                                                                                        \
        _Pragma("unroll")                                                                       \
        for (int ll = 0; ll < BH; ++ll)                                                         \
            __builtin_amdgcn_global_load_lds(                                                   \
                (const AS1 unsigned int*)(Bg0 + (size_t)((hf) * BHR + ll * 64) * Kdim + (kt)),  \
                (AS3 unsigned int*)(&Bs[bf][hf][ll * 4096 + tid * 8]), 16, 0, 0);               \
    } while (0)
#define WAIT_VM_STEADY()                                                                        \
    do {                                                                                        \
        if constexpr (BH == 1)      asm volatile("s_waitcnt vmcnt(2)" ::: "memory");            \
        else if constexpr (BH == 2) asm volatile("s_waitcnt vmcnt(4)" ::: "memory");            \
        else                        asm volatile("s_waitcnt vmcnt(6)" ::: "memory");            \
    } while (0)

    STG_B(0, 0, 0); STG_B(0, 1, 0);
    STG_A(0, 0, 0); STG_A(0, 1, 0);
    if (NT > 1) {
        STG_B(1, 0, 64); STG_B(1, 1, 64);
        WAIT_VM_STEADY();
    } else {
        asm volatile("s_waitcnt vmcnt(0)" ::: "memory");
    }
    __builtin_amdgcn_s_barrier();
    __builtin_amdgcn_sched_barrier(0);

    for (int G = 0; G < NT; ++G) {
        const int cur = G & 1, nxt = cur ^ 1;
        const int ktA = (G + 1) * 64, ktB = (G + 2) * 64;
        const unsigned short* Bh = Bs[cur][bhf];

        bf16x8 bfr[NFRAG][2];
#pragma unroll
        for (int nj = 0; nj < NFRAG; ++nj)
#pragma unroll
            for (int kk = 0; kk < 2; ++kk)
                bfr[nj][kk] = *(const bf16x8*)&Bh[(brb + nj * 16 + ml) * 64 + ((kk * 4 + quad) ^ xr) * 8];

        bf16x8 af[MF][2];
#pragma unroll
        for (int mf = 0; mf < MF; ++mf) {
            const int arow0 = wm * (BM / WM) + mf * 16;
            const int ahf = arow0 / AHR;
            const int arin = arow0 % AHR + ml;
#pragma unroll
            for (int kk = 0; kk < 2; ++kk)
                af[mf][kk] = *(const bf16x8*)&As[cur][ahf][arin * 64 + ((kk * 4 + quad) ^ xr) * 8];
        }

        if (G + 1 < NT) { STG_A(nxt, 0, ktA); STG_A(nxt, 1, ktA); }

        __builtin_amdgcn_s_setprio(1);
#pragma unroll
        for (int kk = 0; kk < 2; ++kk)
#pragma unroll
            for (int mf = 0; mf < MF; ++mf)
#pragma unroll
                for (int nj = 0; nj < NFRAG; ++nj)
                    acc[mf][nj] = __builtin_amdgcn_mfma_f32_16x16x32_bf16(
                        af[mf][kk], bfr[nj][kk], acc[mf][nj], 0, 0, 0);
        __builtin_amdgcn_s_setprio(0);

        asm volatile("s_waitcnt lgkmcnt(0)" ::: "memory");
        __builtin_amdgcn_sched_barrier(0);
        __builtin_amdgcn_s_barrier();

        if (G + 2 < NT) { STG_B(cur, 0, ktB); STG_B(cur, 1, ktB); }
        if (G < NT - 2)       { WAIT_VM_STEADY(); }
        else if (G == NT - 2) { asm volatile("s_waitcnt vmcnt(0)" ::: "memory"); }
        __builtin_amdgcn_sched_barrier(0);
        __builtin_amdgcn_s_barrier();
        __builtin_amdgcn_sched_barrier(0);
    }
#undef STG_A
#undef STG_B
#undef WAIT_VM_STEADY

#pragma unroll
    for (int nj = 0; nj < NFRAG; ++nj) {
        const int col = n0 + wn * (BN / WN) + nj * 16 + ml;
        const float bj = bias[col];
#pragma unroll
        for (int mf = 0; mf < MF; ++mf) {
            const int row0 = m0 + wm * (BM / WM) + mf * 16 + quad * 4;
#pragma unroll
            for (int rr = 0; rr < 4; ++rr) {
                float v = acc[mf][nj][rr] + bj;
                if (BF16OUT)
                    ((unsigned short*)Cv)[(size_t)(row0 + rr) * pitch + col] = f2bf(v);
                else
                    ((float*)Cv)[(size_t)(row0 + rr) * pitch + col] = v;
            }
        }
    }
}

// ---------------- Flash attention: pair-split-KV + LDS k-slot XOR swizzle (r11) --------
__global__ __launch_bounds__(256, 2) void attn_fwd(
    const unsigned short* __restrict__ Qp,
    const unsigned short* __restrict__ Kp,
    const unsigned short* __restrict__ Vt,
    unsigned short* __restrict__ O) {
    const int l = blockIdx.x;
    const int j = l & 15;                 // low q-tile index (0..15)
    const int h = (l >> 4) & 15;
    const int b = l >> 8;
    const int g = h >> 2;
    const int jh = 31 - j;                // high q-tile index (16..31)
    const int tid = threadIdx.x;
    const int w = tid >> 6, lane = tid & 63;
    const int ml = lane & 15, quad = lane >> 4;
    const int rsub = lane >> 2, seg = lane & 3;
    const int pr = w >> 1;                // pair: 0 = A (high 0..16), 1 = B (low, then high tail)
    const int wsub = w & 1;               // 32-row substrip within the pair's q-tile
    const int ssw = (rsub >> 1) & 3;      // staging-side k-slot swizzle (lane-constant)
    const int xsw = (ml >> 1) & 3;        // read-side k-slot swizzle

    __shared__ unsigned short Ks[2][4 * 64 * 32];   // per-pair K tile [kc][krow][32]
    __shared__ unsigned short Vs[2][2 * 128 * 32];  // per-pair V^T tile (sigma order)

    int myqt = pr ? j : jh;
    int q0 = myqt * 64 + wsub * 32;

    bf16x8 aq[2][4];
    auto load_q = [&](int qt) {
#pragma unroll
        for (int g2 = 0; g2 < 2; ++g2) {
            const size_t qrow = (size_t)(b * SDIM + qt * 64 + wsub * 32 + g2 * 16 + ml);
#pragma unroll
            for (int kc = 0; kc < 4; ++kc)
                aq[g2][kc] = *(const bf16x8*)(Qp + qrow * NQKV + h * DKH + kc * 32 + quad * 8);
        }
    };
    load_q(myqt);

    f32x4 o_acc[2][8] = {};
    float l_acc[2] = {0.f, 0.f};

    auto store_out = [&](int qt) {
#pragma unroll
        for (int g2 = 0; g2 < 2; ++g2) {
            float lt = l_acc[g2];
            lt += __shfl_xor(lt, 16);
            lt += __shfl_xor(lt, 32);
            float inv = 1.f / lt;
            size_t rowbase = (size_t)(b * SDIM + qt * 64 + wsub * 32 + g2 * 16 + ml) * DDIM + h * DKH + quad * 4;
#pragma unroll
            for (int dt = 0; dt < 8; ++dt) {
                u16x4 ov;
#pragma unroll
                for (int r = 0; r < 4; ++r)
                    ov[r] = f2bf(o_acc[g2][dt][r] * inv);
                *(u16x4*)(O + rowbase + dt * 16) = ov;
            }
        }
    };

    for (int it = 0; it < 17; ++it) {
        // pair-specific KV tile; kt < 0 => idle iteration (barriers only)
        int kt;
        if (pr == 0)       kt = it;                 // pair A: high tiles 0..16
        else if (it <= j)  kt = it;                 // pair B: low tiles 0..j
        else if (it <= 15) kt = 16 + it - j;        // pair B: high tiles 17..31-j
        else               kt = -1;                 // pair B: idle pad

        __syncthreads();
        if (kt >= 0) {
            const int kb = kt * 64;
            // stage K tile 64x128 into Ks[pr]: source k-chunk pre-swizzled by ssw
#pragma unroll
            for (int kc = 0; kc < 4; ++kc)
#pragma unroll
                for (int rh = 0; rh < 2; ++rh)
                    __builtin_amdgcn_global_load_lds(
                        (const AS1 unsigned int*)(Kp + (size_t)(b * SDIM + kb + rh * 32 + wsub * 16 + rsub) * NQKV + g * DKH + kc * 32 + (seg ^ ssw) * 8),
                        (AS3 unsigned int*)(&Ks[pr][kc * 2048 + rh * 1024 + wsub * 512 + lane * 8]), 16, 0, 0);
            // stage V^T tile (128 d x 64 kv): source kv-chunk pre-swizzled by ssw
#pragma unroll
            for (int c = 0; c < 8; ++c) {
                int u = wsub * 8 + c, kc2 = u >> 3, rg = u & 7;
                __builtin_amdgcn_global_load_lds(
                    (const AS1 unsigned int*)(Vt + (size_t)(b * NKV + g * DKH + rg * 16 + rsub) * SDIM + kb + kc2 * 32 + (seg ^ ssw) * 8),
                    (AS3 unsigned int*)(&Vs[pr][u * 512 + lane * 8]), 16, 0, 0);
            }
        }
        __syncthreads();

        // pair B phase switch: low strip complete -> store it, re-arm for high tail
        if (pr == 1 && it == j + 1) {
            store_out(j);
            myqt = jh; q0 = myqt * 64 + wsub * 32;
            load_q(jh);
#pragma unroll
            for (int g2 = 0; g2 < 2; ++g2) {
                l_acc[g2] = 0.f;
#pragma unroll
                for (int dt = 0; dt < 8; ++dt) o_acc[g2][dt] = (f32x4){0.f, 0.f, 0.f, 0.f};
            }
        }

        if (kt >= 0) {
            const int kb = kt * 64;
            __builtin_amdgcn_s_setprio(1);
            // S^T: A=K (m=kv), B=Q (n=q). st[g2][t][r]: kv=kb+16t+4*quad+r, q=q0+g2*16+ml
            f32x4 st[2][4];
#pragma unroll
            for (int t = 0; t < 4; ++t) {
                bf16x8 ak[4];
#pragma unroll
                for (int kc = 0; kc < 4; ++kc)
                    ak[kc] = *(const bf16x8*)&Ks[pr][kc * 2048 + (t * 16 + ml) * 32 + (quad ^ xsw) * 8];
#pragma unroll
                for (int g2 = 0; g2 < 2; ++g2) {
                    f32x4 sc = {};
#pragma unroll
                    for (int kc = 0; kc < 4; ++kc)
                        sc = __builtin_amdgcn_mfma_f32_16x16x32_bf16(ak[kc], aq[g2][kc], sc, 0, 0, 0);
                    st[g2][t] = sc;
                }
            }

            if (kb + 63 > q0) {  // diagonal tile: causal mask
#pragma unroll
                for (int g2 = 0; g2 < 2; ++g2) {
                    int qg = q0 + g2 * 16 + ml;
#pragma unroll
                    for (int t = 0; t < 4; ++t) {
                        int kvb = kb + t * 16 + quad * 4;
#pragma unroll
                        for (int r = 0; r < 4; ++r)
                            if (kvb + r > qg) st[g2][t][r] = -INFINITY;
                    }
                }
            }

            // fixed-m softmax: p = exp(s - 20), accumulate l in-lane
            unsigned int pk[2][4][2];
#pragma unroll
            for (int g2 = 0; g2 < 2; ++g2) {
#pragma unroll
                for (int t = 0; t < 4; ++t) {
                    float p0 = __expf(st[g2][t][0] - 20.f);
                    float p1 = __expf(st[g2][t][1] - 20.f);
                    float p2 = __expf(st[g2][t][2] - 20.f);
                    float p3 = __expf(st[g2][t][3] - 20.f);
                    l_acc[g2] += (p0 + p1) + (p2 + p3);
                    pk[g2][t][0] = pack2bf(p0, p1);
                    pk[g2][t][1] = pack2bf(p2, p3);
                }
            }

            // PV: O^T += V^T * P^T ; each av read feeds both g2 groups
#pragma unroll
            for (int c = 0; c < 2; ++c) {
                union { unsigned int u[4]; bf16x8 v; } pb[2];
#pragma unroll
                for (int g2 = 0; g2 < 2; ++g2) {
                    pb[g2].u[0] = pk[g2][2 * c][0];     pb[g2].u[1] = pk[g2][2 * c][1];
                    pb[g2].u[2] = pk[g2][2 * c + 1][0]; pb[g2].u[3] = pk[g2][2 * c + 1][1];
                }
#pragma unroll
                for (int dt = 0; dt < 8; ++dt) {
                    bf16x8 av = *(const bf16x8*)&Vs[pr][c * 4096 + (dt * 16 + ml) * 32 + (quad ^ xsw) * 8];
                    o_acc[0][dt] = __builtin_amdgcn_mfma_f32_16x16x32_bf16(av, pb[0].v, o_acc[0][dt], 0, 0, 0);
                    o_acc[1][dt] = __builtin_amdgcn_mfma_f32_16x16x32_bf16(av, pb[1].v, o_acc[1][dt], 0, 0, 0);
                }
            }
            __builtin_amdgcn_s_setprio(0);
        }
    }

    // combine: pair A's q_high partial -> pair B (LDS reuse; conflict-balanced f32x4 layout)
    __syncthreads();
    float* Fo = (float*)&Ks[0][0];   // 8192 floats (32 KB) == 2 waves x 64 lanes x 64 f32
    float* Fl = (float*)&Vs[0][0];   // 256 floats
    if (pr == 0) {
#pragma unroll
        for (int g2 = 0; g2 < 2; ++g2) {
            Fl[(g2 * 2 + wsub) * 64 + lane] = l_acc[g2];
#pragma unroll
            for (int dt = 0; dt < 8; ++dt)
                *(f32x4*)&Fo[(g2 * 8 + dt) * 512 + wsub * 256 + lane * 4] = o_acc[g2][dt];
        }
    }
    __syncthreads();
    if (pr == 1) {
#pragma unroll
        for (int g2 = 0; g2 < 2; ++g2) {
            l_acc[g2] += Fl[(g2 * 2 + wsub) * 64 + lane];
#pragma unroll
            for (int dt = 0; dt < 8; ++dt) {
                f32x4 pa = *(const f32x4*)&Fo[(g2 * 8 + dt) * 512 + wsub * 256 + lane * 4];
#pragma unroll
                for (int r = 0; r < 4; ++r) o_acc[g2][dt][r] += pa[r];
            }
        }
        store_out(jh);
    }
}

// ---------------- host launch ----------------
extern "C" void kernel_launch(void* const* d_in, const int* in_sizes, int n_in,
                              void* d_out, int out_size, void* d_ws, size_t ws_size,
                              hipStream_t stream) {
    const float* x    = (const float*)d_in[0];
    const float* fcos = (const float*)d_in[1];
    const float* fsin = (const float*)d_in[2];
    const float* wq_w = (const float*)d_in[3];
    const float* wq_b = (const float*)d_in[4];
    const float* wk_w = (const float*)d_in[5];
    const float* wk_b = (const float*)d_in[6];
    const float* wv_w = (const float*)d_in[7];
    const float* wv_b = (const float*)d_in[8];
    const float* wo_w = (const float*)d_in[9];
    const float* wo_b = (const float*)d_in[10];
    float* out = (float*)d_out;

    char* ws = (char*)d_ws;
    size_t off = 0;
    auto alloc = [&](size_t bytes) {
        char* p = ws + off;
        off += (bytes + 255) & ~(size_t)255;
        return p;
    };
    // NOTE: xb|W3|wob must be contiguous (cast_all writes them as one range)
    unsigned short* xb  = (unsigned short*)alloc(NX * 2);
    unsigned short* W3  = (unsigned short*)alloc((size_t)NQKV * DDIM * 2);
    unsigned short* wob = (unsigned short*)alloc(NWQ * 2);
    float* b3           = (float*)alloc((size_t)NQKV * 4);
    unsigned short* qkv = (unsigned short*)alloc((size_t)MROWS * NQKV * 2);
    unsigned short* Vt  = (unsigned short*)alloc((size_t)BDIM * NKV * SDIM * 2);
    unsigned short* att = (unsigned short*)alloc((size_t)MROWS * DDIM * 2);

    cast_all<<<dim3(CAST_BLOCKS + 12), dim3(256), 0, stream>>>(
        x, wq_w, wk_w, wv_w, wo_w, xb, wq_b, wk_b, wv_b, b3);

    // fused QKV projection: 128x384 tile, register-pipelined (r13 best: 62.8 us)
    gemm_rp<1, 128, 384, 1, 8><<<dim3(NQKV / 384, MROWS / 128), 512, 0, stream>>>(
        xb, W3, b3, qkv, NQKV, DDIM);

    const float scale = 0.08838834764831845f;  // 1/sqrt(128), folded into Q
    rope_trans<<<dim3(MROWS + 2048), dim3(320), 0, stream>>>(qkv, fcos, fsin, Vt, scale);

    attn_fwd<<<dim3(512), dim3(256), 0, stream>>>(qkv, qkv + DDIM, Vt, att);

    // output projection (f32 out): 256x128 tile, 2-barrier (r11 best) -> 256 blocks
    gemm2b<0, 256, 128, 2, 4><<<dim3(DDIM / 128, MROWS / 256), 512, 0, stream>>>(
        att, wob, wo_b, out, DDIM, DDIM);
}